// Round 8
// baseline (1124.089 us; speedup 1.0000x reference)
//
#include <hip/hip_runtime.h>

// CG tensor-product iteration: per sample n, 34 (l1,l2,L) combos of
//   b[n,M,p,q] = sum_{i,j} x1_{l1}[n,i,p] * x2_{l2}[n,j,q] * C[i,j,M]
// packed into a (n, 39936) f32 row, keys (L,S) sorted, blocks concatenated.
// Output 639 MB write-dominated; ~7 GFLOP.
//
// Evidence: R1 (scattered scalar, no barriers) == R3 (scattered 1KB staged)
// == 166-169us @3.85 TB/s; fill (linear) = 6.6 TB/s -> DRAM-row locality.
// R6 (linear per-block writes) starved: VGPR 132 -> 3 blocks/CU, and
// __syncthreads() drained vmcnt(0) every pass -> 1.58 TB/s. R7 (VMEM coeff
// loads) 592us -> scalar coeff path exonerated.
// This round: R6 linear pattern + sustained pressure:
//   (1) pipe barrier = s_waitcnt lgkmcnt(0) + raw s_barrier (stores stay
//       in flight across passes; vmcnt never force-drained to 0),
//   (2) sched_barrier(0) fences between passes (stop cross-pass VGPR bloat),
//   (3) __launch_bounds__(256,5) -> >=5 blocks/CU.

namespace {

typedef float f32x4 __attribute__((ext_vector_type(4)));

constexpr int NC = 34;
constexpr int SEGF = 3072;  // pass size in floats (12 KB per buffer)

struct CInfo { int l1, l2, L, s, pbase, blk, nb, segbase; };
struct PInfo { int kidx, M0, M1, base, floats; };
struct Tables {
  CInfo c[NC];
  PInfo p[24];
  int np;
  int packed_total;
  int outsize;
};

constexpr Tables build() {
  Tables t{};
  // key index k = L*2 + s, s: 0 -> S=-1, 1 -> S=+1 (sorted key order)
  int nb[8] = {};
  for (int l1 = 0; l1 < 4; ++l1)
    for (int l2 = 0; l2 < 4; ++l2) {
      int lo = l1 > l2 ? l1 - l2 : l2 - l1;
      int hi = (l1 + l2 < 3) ? l1 + l2 : 3;
      for (int L = lo; L <= hi; ++L)
        nb[L * 2 + (((l1 + l2 + L) & 1) ? 0 : 1)]++;
    }
  int segbase[8] = {};
  int off = 0;
  for (int k = 0; k < 8; ++k) {
    segbase[k] = off;
    off += (2 * (k >> 1) + 1) * 256 * nb[k];
  }
  t.outsize = off;
  // combos in reference iteration order
  int blk[8] = {};
  int idx = 0, pb = 0;
  for (int l1 = 0; l1 < 4; ++l1)
    for (int l2 = 0; l2 < 4; ++l2) {
      int lo = l1 > l2 ? l1 - l2 : l2 - l1;
      int hi = (l1 + l2 < 3) ? l1 + l2 : 3;
      for (int L = lo; L <= hi; ++L) {
        int s = ((l1 + l2 + L) & 1) ? 0 : 1;
        int k = L * 2 + s;
        pb = (pb + 15) & ~15;
        t.c[idx].l1 = l1; t.c[idx].l2 = l2; t.c[idx].L = L; t.c[idx].s = s;
        t.c[idx].pbase = pb;
        t.c[idx].blk = blk[k];
        t.c[idx].nb = nb[k];
        t.c[idx].segbase = segbase[k];
        blk[k]++;
        pb += (2 * l1 + 1) * (2 * l2 + 1) * (2 * L + 1);
        ++idx;
      }
    }
  t.packed_total = pb;
  // passes: chunk each key's (2L+1) super-rows (nb*256 floats each) to <=SEGF
  int np = 0;
  for (int k = 0; k < 8; ++k) {
    if (nb[k] == 0) continue;
    int DL = 2 * (k >> 1) + 1;
    int sr = nb[k] * 256;
    int maxsr = SEGF / sr;
    int M0 = 0;
    while (M0 < DL) {
      int M1 = M0 + maxsr < DL ? M0 + maxsr : DL;
      t.p[np].kidx = k; t.p[np].M0 = M0; t.p[np].M1 = M1;
      t.p[np].base = segbase[k] + M0 * sr;
      t.p[np].floats = (M1 - M0) * sr;
      ++np;
      M0 = M1;
    }
  }
  t.np = np;
  return t;
}

constexpr Tables TAB = build();
static_assert(TAB.outsize == 39936, "output layout mismatch");
static_assert(TAB.packed_total <= 4096, "packed cg exceeds 16KB");
static_assert(TAB.np <= 24, "too many passes");

// ---- coefficient pre-pack: gather cg[l1,l2,L,i,j,M] into contiguous,
// combo-major, (i,j,M)-ordered table in workspace (read order of main loop).
template <int CI>
__device__ __forceinline__ void pack_combo(const float* __restrict__ cg,
                                           float* __restrict__ cgp, int tid) {
  if constexpr (CI < NC) {
    constexpr CInfo c = TAB.c[CI];
    constexpr int D2 = 2 * c.l2 + 1, DL = 2 * c.L + 1;
    constexpr int SZ = (2 * c.l1 + 1) * D2 * DL;
    for (int tt = tid; tt < SZ; tt += 256) {
      int M = tt % DL, ij = tt / DL;
      int j = ij % D2, i = ij / D2;
      cgp[c.pbase + tt] =
          cg[((((c.l1 * 4 + c.l2) * 4 + c.L) * 7 + i) * 7 + j) * 7 + M];
    }
    pack_combo<CI + 1>(cg, cgp, tid);
  }
}

__global__ void pack_cg_kernel(const float* __restrict__ cg,
                               float* __restrict__ cgp) {
  pack_combo<0>(cg, cgp, (int)threadIdx.x);
}

// ---- main: one block per sample, thread = (p = tid>>4, q = tid&15).
// Pipeline: flush(pass k from buf k&1) -> compute(pass k+1 into buf ~(k&1))
// -> lgkm-only barrier (global stores stay in flight).
template <int PI, int CI>
__device__ __forceinline__ void pass_combos(const float* __restrict__ cgp,
                                            const float (&x1r)[16],
                                            const float (&x2r)[16],
                                            float* __restrict__ seg, int tid) {
  if constexpr (CI < NC) {
    constexpr PInfo P = TAB.p[PI];
    constexpr CInfo c = TAB.c[CI];
    if constexpr (c.L * 2 + c.s == P.kidx) {
      constexpr int D1 = 2 * c.l1 + 1, D2 = 2 * c.l2 + 1, DL = 2 * c.L + 1;
      constexpr int R1 = c.l1 * c.l1, R2 = c.l2 * c.l2;  // row bases: l^2
      constexpr int NA = P.M1 - P.M0;
      float acc[NA];
#pragma unroll
      for (int m = 0; m < NA; ++m) acc[m] = 0.f;
#pragma unroll
      for (int i = 0; i < D1; ++i) {
#pragma unroll
        for (int j = 0; j < D2; ++j) {
          const float ab = x1r[R1 + i] * x2r[R2 + j];
#pragma unroll
          for (int m = 0; m < NA; ++m)
            acc[m] = fmaf(cgp[c.pbase + (i * D2 + j) * DL + P.M0 + m], ab,
                          acc[m]);
        }
      }
#pragma unroll
      for (int m = 0; m < NA; ++m)
        seg[m * (c.nb * 256) + c.blk * 256 + tid] = acc[m];
    }
    pass_combos<PI, CI + 1>(cgp, x1r, x2r, seg, tid);
  }
}

template <int PI>
__device__ __forceinline__ void flush_pass(const float* __restrict__ seg,
                                           float* __restrict__ outn, int tid) {
  constexpr PInfo P = TAB.p[PI];
  constexpr int NF4 = P.floats / 4;
  const f32x4* sb = reinterpret_cast<const f32x4*>(seg);
  f32x4* ob = reinterpret_cast<f32x4*>(outn + P.base);
#pragma unroll
  for (int k = 0; k < (NF4 + 255) / 256; ++k) {
    const int idx = tid + 256 * k;
    if constexpr ((NF4 & 255) == 0) {
      ob[idx] = sb[idx];
    } else {
      if (idx < NF4) ob[idx] = sb[idx];
    }
  }
}

// Barrier that drains LDS ops only: global stores remain in flight (the
// compiler's __syncthreads would emit s_waitcnt vmcnt(0) and stall the
// store pipeline every pass).
__device__ __forceinline__ void lds_barrier() {
  __builtin_amdgcn_sched_barrier(0);
  asm volatile("s_waitcnt lgkmcnt(0)" ::: "memory");
  __builtin_amdgcn_s_barrier();
  __builtin_amdgcn_sched_barrier(0);
}

template <int PI>
__device__ __forceinline__ void pipe(const float* __restrict__ cgp,
                                     const float (&x1r)[16],
                                     const float (&x2r)[16],
                                     float* __restrict__ stage,
                                     float* __restrict__ outn, int tid) {
  if constexpr (PI < TAB.np) {
    // issue stores for pass PI (reads buf PI&1)
    flush_pass<PI>(stage + (PI & 1) * SEGF, outn, tid);
    __builtin_amdgcn_sched_barrier(0);
    // compute next pass into the other buffer while stores drain
    if constexpr (PI + 1 < TAB.np)
      pass_combos<PI + 1, 0>(cgp, x1r, x2r, stage + ((PI + 1) & 1) * SEGF,
                             tid);
    lds_barrier();
    pipe<PI + 1>(cgp, x1r, x2r, stage, outn, tid);
  }
}

__global__ __launch_bounds__(256, 5) void cg_main(
    const float* __restrict__ x1_0, const float* __restrict__ x2_0,
    const float* __restrict__ x1_1, const float* __restrict__ x2_1,
    const float* __restrict__ x1_2, const float* __restrict__ x2_2,
    const float* __restrict__ x1_3, const float* __restrict__ x2_3,
    const float* __restrict__ cgp_, float* __restrict__ out) {
  const float* cgp = (const float*)__builtin_assume_aligned(cgp_, 256);
  __shared__ float x1s[16][16];  // row = lm index (l^2 + i), col = Q
  __shared__ float x2s[16][16];
  __shared__ __align__(16) float stage[2 * SEGF];  // 2 x 12 KB pass buffers
  const int tid = (int)threadIdx.x;
  const int n = (int)blockIdx.x;
  const int r = tid >> 4, col = tid & 15;
  // stage this sample's 2*256 input floats (each thread: 1 x1 + 1 x2 elem)
  const float* s1; const float* s2; int ri;
  if (r < 1)      { s1 = x1_0 + n * 16;  s2 = x2_0 + n * 16;  ri = r; }
  else if (r < 4) { s1 = x1_1 + n * 48;  s2 = x2_1 + n * 48;  ri = r - 1; }
  else if (r < 9) { s1 = x1_2 + n * 80;  s2 = x2_2 + n * 80;  ri = r - 4; }
  else            { s1 = x1_3 + n * 112; s2 = x2_3 + n * 112; ri = r - 9; }
  x1s[r][col] = s1[ri * 16 + col];
  x2s[r][col] = s2[ri * 16 + col];
  __syncthreads();
  // hoist this thread's columns into registers (compile-time indexed)
  float x1r[16], x2r[16];
#pragma unroll
  for (int k = 0; k < 16; ++k) {
    x1r[k] = x1s[k][r];    // p = r
    x2r[k] = x2s[k][col];  // q = col
  }
  float* outn = out + (size_t)n * (size_t)TAB.outsize;
  // prologue: compute pass 0 into buf0, then enter the pipelined loop
  pass_combos<0, 0>(cgp, x1r, x2r, stage, tid);
  lds_barrier();
  pipe<0>(cgp, x1r, x2r, stage, outn, tid);
}

}  // namespace

extern "C" void kernel_launch(void* const* d_in, const int* in_sizes, int n_in,
                              void* d_out, int out_size, void* d_ws,
                              size_t ws_size, hipStream_t stream) {
  const float* x1[4];
  const float* x2[4];
  // setup_inputs() dict order is interleaved (x1_l0, x2_l0, x1_l1, ...);
  // detect vs grouped (x1_l0..x1_l3, x2_l0..) via sizes.
  if (in_sizes[1] == in_sizes[0]) {
    for (int l = 0; l < 4; ++l) {
      x1[l] = (const float*)d_in[2 * l];
      x2[l] = (const float*)d_in[2 * l + 1];
    }
  } else {
    for (int l = 0; l < 4; ++l) {
      x1[l] = (const float*)d_in[l];
      x2[l] = (const float*)d_in[4 + l];
    }
  }
  const float* cg = (const float*)d_in[8];
  float* out = (float*)d_out;
  float* cgp = (float*)d_ws;  // packed coefficients (~16 KB)

  const int n = in_sizes[0] / 16;  // x?_l0 is (n, 1, 16)

  pack_cg_kernel<<<1, 256, 0, stream>>>(cg, cgp);
  cg_main<<<n, 256, 0, stream>>>(x1[0], x2[0], x1[1], x2[1], x1[2], x2[2],
                                 x1[3], x2[3], cgp, out);
}

// Round 10
// 233.545 us; speedup vs baseline: 4.8132x; 4.8132x over previous
//
#include <hip/hip_runtime.h>

// CG tensor-product iteration: per sample n, 34 (l1,l2,L) combos of
//   b[n,M,p,q] = sum_{i,j} x1_{l1}[n,i,p] * x2_{l2}[n,j,q] * C[i,j,M]
// packed into a (n, 39936) f32 row, keys (L,S) sorted, blocks concatenated.
// Output 639 MB write-dominated; ~7 GFLOP.
//
// Evidence: R1 scatter==R3 staged-scatter (166us, 3.85 TB/s) vs fill 6.6
// TB/s -> write-front density theory. R5-R8 attempts died of register
// pressure artifacts. R9: block = (sample, key) -> one contiguous 4-42KB
// segment, XCD-chunked mapping for a dense per-XCD linear write front —
// but a wrong "empty key" guess (case 1 skipped; actually key 0 is the
// empty one) zeroed the (L=0,S=+1) segment. This round: identical, with
// the switch dispatching ALL keys (empty key no-ops naturally).

namespace {

typedef float f32x4 __attribute__((ext_vector_type(4)));

constexpr int NC = 34;
constexpr int NKEY = 8;

struct CInfo { int l1, l2, L, s, pbase, blk; };
struct KInfo { int nb, segbase, segfloats; };
struct Tables { CInfo c[NC]; KInfo k[NKEY]; int packed_total; int outsize; int segmax; };

constexpr Tables build() {
  Tables t{};
  // key index k = L*2 + s, s: 0 -> S=-1, 1 -> S=+1 (sorted key order)
  int nb[NKEY] = {};
  for (int l1 = 0; l1 < 4; ++l1)
    for (int l2 = 0; l2 < 4; ++l2) {
      int lo = l1 > l2 ? l1 - l2 : l2 - l1;
      int hi = (l1 + l2 < 3) ? l1 + l2 : 3;
      for (int L = lo; L <= hi; ++L)
        nb[L * 2 + (((l1 + l2 + L) & 1) ? 0 : 1)]++;
    }
  int segbase[NKEY] = {};
  int off = 0;
  for (int k = 0; k < NKEY; ++k) {
    segbase[k] = off;
    off += (2 * (k >> 1) + 1) * 256 * nb[k];
  }
  t.outsize = off;
  // combos in reference iteration order; packed-coeff bases 16-aligned
  int blk[NKEY] = {};
  int idx = 0, pb = 0;
  for (int l1 = 0; l1 < 4; ++l1)
    for (int l2 = 0; l2 < 4; ++l2) {
      int lo = l1 > l2 ? l1 - l2 : l2 - l1;
      int hi = (l1 + l2 < 3) ? l1 + l2 : 3;
      for (int L = lo; L <= hi; ++L) {
        int s = ((l1 + l2 + L) & 1) ? 0 : 1;
        int k = L * 2 + s;
        pb = (pb + 15) & ~15;
        t.c[idx].l1 = l1; t.c[idx].l2 = l2; t.c[idx].L = L; t.c[idx].s = s;
        t.c[idx].pbase = pb;
        t.c[idx].blk = blk[k];
        blk[k]++;
        pb += (2 * l1 + 1) * (2 * l2 + 1) * (2 * L + 1);
        ++idx;
      }
    }
  t.packed_total = pb;
  int mx = 0;
  for (int k = 0; k < NKEY; ++k) {
    t.k[k].nb = nb[k];
    t.k[k].segbase = segbase[k];
    t.k[k].segfloats = (2 * (k >> 1) + 1) * 256 * nb[k];
    if (t.k[k].segfloats > mx) mx = t.k[k].segfloats;
  }
  t.segmax = mx;
  return t;
}

constexpr Tables TAB = build();
static_assert(TAB.outsize == 39936, "output layout mismatch");
static_assert(TAB.packed_total <= 4096, "packed cg exceeds 16KB");
static_assert(TAB.segmax == 10752, "unexpected max segment");
static_assert(TAB.k[0].segfloats == 0, "key 0 (L=0,S=-1) should be empty");
static_assert(TAB.k[1].segfloats == 1024, "key 1 (L=0,S=+1) should be 4 blocks");

// ---- coefficient pre-pack: gather cg[l1,l2,L,i,j,M] into contiguous,
// combo-major, (i,j,M)-ordered table in workspace (read order of main loop).
template <int CI>
__device__ __forceinline__ void pack_combo(const float* __restrict__ cg,
                                           float* __restrict__ cgp, int tid) {
  if constexpr (CI < NC) {
    constexpr CInfo c = TAB.c[CI];
    constexpr int D2 = 2 * c.l2 + 1, DL = 2 * c.L + 1;
    constexpr int SZ = (2 * c.l1 + 1) * D2 * DL;
    for (int tt = tid; tt < SZ; tt += 256) {
      int M = tt % DL, ij = tt / DL;
      int j = ij % D2, i = ij / D2;
      cgp[c.pbase + tt] =
          cg[((((c.l1 * 4 + c.l2) * 4 + c.L) * 7 + i) * 7 + j) * 7 + M];
    }
    pack_combo<CI + 1>(cg, cgp, tid);
  }
}

__global__ void pack_cg_kernel(const float* __restrict__ cg,
                               float* __restrict__ cgp) {
  pack_combo<0>(cg, cgp, (int)threadIdx.x);
}

// ---- per-key compute: thread = (p = tid>>4, q = tid&15); for each combo
// of key K, accumulate acc[DL] and stage at seg[M][blk*256 + tid].
template <int K, int CI>
__device__ __forceinline__ void key_combos(const float* __restrict__ cgp,
                                           const float (&x1r)[16],
                                           const float (&x2r)[16],
                                           float* __restrict__ seg, int tid) {
  if constexpr (CI < NC) {
    constexpr CInfo c = TAB.c[CI];
    if constexpr (c.L * 2 + c.s == K) {
      constexpr int D1 = 2 * c.l1 + 1, D2 = 2 * c.l2 + 1, DL = 2 * c.L + 1;
      constexpr int R1 = c.l1 * c.l1, R2 = c.l2 * c.l2;  // row bases: l^2
      constexpr int NBC = TAB.k[K].nb * 256;
      float acc[DL];
#pragma unroll
      for (int M = 0; M < DL; ++M) acc[M] = 0.f;
#pragma unroll
      for (int i = 0; i < D1; ++i) {
#pragma unroll
        for (int j = 0; j < D2; ++j) {
          const float ab = x1r[R1 + i] * x2r[R2 + j];
#pragma unroll
          for (int M = 0; M < DL; ++M)
            acc[M] = fmaf(cgp[c.pbase + (i * D2 + j) * DL + M], ab, acc[M]);
        }
      }
#pragma unroll
      for (int M = 0; M < DL; ++M)
        seg[M * NBC + c.blk * 256 + tid] = acc[M];
    }
    key_combos<K, CI + 1>(cgp, x1r, x2r, seg, tid);
  }
}

template <int K>
__device__ __forceinline__ void do_key(const float* __restrict__ cgp,
                                       const float (&x1r)[16],
                                       const float (&x2r)[16],
                                       float* __restrict__ seg,
                                       float* __restrict__ outseg, int tid) {
  if constexpr (TAB.k[K].segfloats > 0) {
    key_combos<K, 0>(cgp, x1r, x2r, seg, tid);
    __syncthreads();
    constexpr int NF4 = TAB.k[K].segfloats / 4;
    const f32x4* sb = reinterpret_cast<const f32x4*>(seg);
    f32x4* ob = reinterpret_cast<f32x4*>(outseg);
#pragma unroll
    for (int k0 = 0; k0 < (NF4 + 255) / 256; ++k0) {
      const int idx = tid + 256 * k0;
      if constexpr ((NF4 & 255) == 0) {
        ob[idx] = sb[idx];
      } else {
        if (idx < NF4) ob[idx] = sb[idx];
      }
    }
  }
}

// ---- main: block = (sample, key). XCD-chunked mapping: blocks on XCD x
// (id%8 == x) cover the contiguous flat range [x*nsamp, (x+1)*nsamp), so
// each XCD sweeps a contiguous 1/8 of the output monotonically.
__global__ __launch_bounds__(256) void cg_main(
    const float* __restrict__ x1_0, const float* __restrict__ x2_0,
    const float* __restrict__ x1_1, const float* __restrict__ x2_1,
    const float* __restrict__ x1_2, const float* __restrict__ x2_2,
    const float* __restrict__ x1_3, const float* __restrict__ x2_3,
    const float* __restrict__ cgp_, float* __restrict__ out, int nsamp) {
  const float* cgp = (const float*)__builtin_assume_aligned(cgp_, 256);
  __shared__ float x1s[16][16];  // row = lm index (l^2 + i), col = Q
  __shared__ float x2s[16][16];
  __shared__ __align__(16) float seg[TAB.segmax];  // 42 KB segment staging
  const int tid = (int)threadIdx.x;
  const int id = (int)blockIdx.x;
  const int xcd = id & 7, g = id >> 3;
  const int flat = xcd * nsamp + g;  // address-ordered (n, key) index
  const int n = flat >> 3;
  const int key = flat & 7;
  const int r = tid >> 4, col = tid & 15;
  // stage this sample's 2*256 input floats (each thread: 1 x1 + 1 x2 elem)
  const float* s1; const float* s2; int ri;
  if (r < 1)      { s1 = x1_0 + n * 16;  s2 = x2_0 + n * 16;  ri = r; }
  else if (r < 4) { s1 = x1_1 + n * 48;  s2 = x2_1 + n * 48;  ri = r - 1; }
  else if (r < 9) { s1 = x1_2 + n * 80;  s2 = x2_2 + n * 80;  ri = r - 4; }
  else            { s1 = x1_3 + n * 112; s2 = x2_3 + n * 112; ri = r - 9; }
  x1s[r][col] = s1[ri * 16 + col];
  x2s[r][col] = s2[ri * 16 + col];
  __syncthreads();
  // hoist this thread's columns into registers (compile-time indexed)
  float x1r[16], x2r[16];
#pragma unroll
  for (int k = 0; k < 16; ++k) {
    x1r[k] = x1s[k][r];    // p = r
    x2r[k] = x2s[k][col];  // q = col
  }
  float* outrow = out + (size_t)n * (size_t)TAB.outsize;
  switch (key) {
    case 0: do_key<0>(cgp, x1r, x2r, seg, outrow + TAB.k[0].segbase, tid); break;
    case 1: do_key<1>(cgp, x1r, x2r, seg, outrow + TAB.k[1].segbase, tid); break;
    case 2: do_key<2>(cgp, x1r, x2r, seg, outrow + TAB.k[2].segbase, tid); break;
    case 3: do_key<3>(cgp, x1r, x2r, seg, outrow + TAB.k[3].segbase, tid); break;
    case 4: do_key<4>(cgp, x1r, x2r, seg, outrow + TAB.k[4].segbase, tid); break;
    case 5: do_key<5>(cgp, x1r, x2r, seg, outrow + TAB.k[5].segbase, tid); break;
    case 6: do_key<6>(cgp, x1r, x2r, seg, outrow + TAB.k[6].segbase, tid); break;
    case 7: do_key<7>(cgp, x1r, x2r, seg, outrow + TAB.k[7].segbase, tid); break;
  }
}

}  // namespace

extern "C" void kernel_launch(void* const* d_in, const int* in_sizes, int n_in,
                              void* d_out, int out_size, void* d_ws,
                              size_t ws_size, hipStream_t stream) {
  const float* x1[4];
  const float* x2[4];
  // setup_inputs() dict order is interleaved (x1_l0, x2_l0, x1_l1, ...);
  // detect vs grouped (x1_l0..x1_l3, x2_l0..) via sizes.
  if (in_sizes[1] == in_sizes[0]) {
    for (int l = 0; l < 4; ++l) {
      x1[l] = (const float*)d_in[2 * l];
      x2[l] = (const float*)d_in[2 * l + 1];
    }
  } else {
    for (int l = 0; l < 4; ++l) {
      x1[l] = (const float*)d_in[l];
      x2[l] = (const float*)d_in[4 + l];
    }
  }
  const float* cg = (const float*)d_in[8];
  float* out = (float*)d_out;
  float* cgp = (float*)d_ws;  // packed coefficients (~16 KB)

  const int n = in_sizes[0] / 16;  // x?_l0 is (n, 1, 16)

  pack_cg_kernel<<<1, 256, 0, stream>>>(cg, cgp);
  cg_main<<<8 * n, 256, 0, stream>>>(x1[0], x2[0], x1[1], x2[1], x1[2],
                                     x2[2], x1[3], x2[3], cgp, out, n);
}

// Round 11
// 163.936 us; speedup vs baseline: 6.8569x; 1.4246x over previous
//
#include <hip/hip_runtime.h>

// CG tensor-product iteration: per sample n, 34 (l1,l2,L) combos of
//   b[n,M,p,q] = sum_{i,j} x1_{l1}[n,i,p] * x2_{l2}[n,j,q] * C[i,j,M]
// packed into a (n, 39936) f32 row, keys (L,S) sorted, blocks concatenated.
// Output 639 MB write-dominated; ~7 GFLOP.
//
// R1 scatter == R3 staged-scatter (166us, 3.85 TB/s) vs fill 6.6 TB/s.
// R5-R8: pipelined linear fronts died of spills / forced drains. R10:
// (sample,key) blocks -> x8 prologues, 3 blocks/CU -> 233us. Still no
// clean test of the write-front theory.
// This round: block = HALF a sample row. Half A = keys {1,2,3,4,6} (79KB
// LDS), half B = keys {5,7} (77KB); any 2 blocks pair under 160KB -> 2
// blocks/CU, 16 waves, no VGPR tricks. 512 threads = 2 combo-groups
// (constexpr greedy-balanced). One barrier, flush 2 long linear spans,
// stores drain only at endpgm under the co-resident block's compute.

namespace {

typedef float f32x4 __attribute__((ext_vector_type(4)));

constexpr int NC = 34;
constexpr int NKEY = 8;

struct CInfo { int l1, l2, L, key, pbase, blk, nbc, half, grp, lbase; };
struct Span { int gbase, lbase, nf; };       // floats
struct HInfo { int segf; Span sp[2]; };
struct Tables {
  CInfo c[NC];
  HInfo h[2];
  int packed_total;
  int outsize;
};

constexpr int halfof(int key) { return (key == 5 || key == 7) ? 1 : 0; }

constexpr Tables build() {
  Tables t{};
  // key index k = L*2 + s, s: 0 -> S=-1, 1 -> S=+1 (sorted key order)
  int nb[NKEY] = {};
  for (int l1 = 0; l1 < 4; ++l1)
    for (int l2 = 0; l2 < 4; ++l2) {
      int lo = l1 > l2 ? l1 - l2 : l2 - l1;
      int hi = (l1 + l2 < 3) ? l1 + l2 : 3;
      for (int L = lo; L <= hi; ++L)
        nb[L * 2 + (((l1 + l2 + L) & 1) ? 0 : 1)]++;
    }
  int keyf[NKEY] = {}, keyoff[NKEY] = {};
  int off = 0;
  for (int k = 0; k < NKEY; ++k) {
    keyf[k] = (2 * (k >> 1) + 1) * 256 * nb[k];
    keyoff[k] = off;
    off += keyf[k];
  }
  t.outsize = off;
  // local (per-half LDS) bases
  int lbase[NKEY] = {};
  {
    int o0 = 0, o1 = 0;
    for (int k = 0; k < NKEY; ++k) {
      if (keyf[k] == 0) { lbase[k] = 0; continue; }
      if (halfof(k) == 0) { lbase[k] = o0; o0 += keyf[k]; }
      else                { lbase[k] = o1; o1 += keyf[k]; }
    }
    t.h[0].segf = o0;
    t.h[1].segf = o1;
  }
  // flush spans: half0 = [keys1..4 contiguous] + [key6]; half1 = [key5]+[key7]
  t.h[0].sp[0] = Span{keyoff[1], lbase[1],
                      keyf[1] + keyf[2] + keyf[3] + keyf[4]};
  t.h[0].sp[1] = Span{keyoff[6], lbase[6], keyf[6]};
  t.h[1].sp[0] = Span{keyoff[5], lbase[5], keyf[5]};
  t.h[1].sp[1] = Span{keyoff[7], lbase[7], keyf[7]};
  // combos in reference iteration order; greedy 2-group balance per half
  int blk[NKEY] = {};
  int gcost[2][2] = {};
  int idx = 0, pb = 0;
  for (int l1 = 0; l1 < 4; ++l1)
    for (int l2 = 0; l2 < 4; ++l2) {
      int lo = l1 > l2 ? l1 - l2 : l2 - l1;
      int hi = (l1 + l2 < 3) ? l1 + l2 : 3;
      for (int L = lo; L <= hi; ++L) {
        int s = ((l1 + l2 + L) & 1) ? 0 : 1;
        int k = L * 2 + s;
        pb = (pb + 15) & ~15;
        int h = halfof(k);
        int cost = (2 * l1 + 1) * (2 * l2 + 1) * (2 * L + 1);
        int g = (gcost[h][0] <= gcost[h][1]) ? 0 : 1;
        gcost[h][g] += cost;
        t.c[idx].l1 = l1; t.c[idx].l2 = l2; t.c[idx].L = L;
        t.c[idx].key = k;
        t.c[idx].pbase = pb;
        t.c[idx].blk = blk[k];
        t.c[idx].nbc = nb[k] * 256;
        t.c[idx].half = h;
        t.c[idx].grp = g;
        t.c[idx].lbase = lbase[k];
        blk[k]++;
        pb += cost;
        ++idx;
      }
    }
  t.packed_total = pb;
  return t;
}

constexpr Tables TAB = build();
static_assert(TAB.outsize == 39936, "output layout mismatch");
static_assert(TAB.packed_total <= 4096, "packed cg exceeds 16KB");
static_assert(TAB.h[0].segf == 20224, "half A should be 79KB");
static_assert(TAB.h[1].segf == 19712, "half B should be 77KB");

// ---- coefficient pre-pack: gather cg[l1,l2,L,i,j,M] into contiguous,
// combo-major, (i,j,M)-ordered table in workspace (read order of main loop).
template <int CI>
__device__ __forceinline__ void pack_combo(const float* __restrict__ cg,
                                           float* __restrict__ cgp, int tid) {
  if constexpr (CI < NC) {
    constexpr CInfo c = TAB.c[CI];
    constexpr int D2 = 2 * c.l2 + 1, DL = 2 * c.L + 1;
    constexpr int SZ = (2 * c.l1 + 1) * D2 * DL;
    for (int tt = tid; tt < SZ; tt += 256) {
      int M = tt % DL, ij = tt / DL;
      int j = ij % D2, i = ij / D2;
      cgp[c.pbase + tt] =
          cg[((((c.l1 * 4 + c.l2) * 4 + c.L) * 7 + i) * 7 + j) * 7 + M];
    }
    pack_combo<CI + 1>(cg, cgp, tid);
  }
}

__global__ void pack_cg_kernel(const float* __restrict__ cg,
                               float* __restrict__ cgp) {
  pack_combo<0>(cg, cgp, (int)threadIdx.x);
}

// ---- group compute: 256-thread group runs its combos; t = tid&255 ->
// (p = t>>4, q = t&15); stage at seg[lbase + M*nbc + blk*256 + t].
template <int HALF, int GRP, int CI>
__device__ __forceinline__ void grp_combos(const float* __restrict__ cgp,
                                           const float (&x1r)[16],
                                           const float (&x2r)[16],
                                           float* __restrict__ seg, int t) {
  if constexpr (CI < NC) {
    constexpr CInfo c = TAB.c[CI];
    if constexpr (c.half == HALF && c.grp == GRP) {
      constexpr int D1 = 2 * c.l1 + 1, D2 = 2 * c.l2 + 1, DL = 2 * c.L + 1;
      constexpr int R1 = c.l1 * c.l1, R2 = c.l2 * c.l2;  // row bases: l^2
      float acc[DL];
#pragma unroll
      for (int M = 0; M < DL; ++M) acc[M] = 0.f;
#pragma unroll
      for (int i = 0; i < D1; ++i) {
#pragma unroll
        for (int j = 0; j < D2; ++j) {
          const float ab = x1r[R1 + i] * x2r[R2 + j];
#pragma unroll
          for (int M = 0; M < DL; ++M)
            acc[M] = fmaf(cgp[c.pbase + (i * D2 + j) * DL + M], ab, acc[M]);
        }
      }
#pragma unroll
      for (int M = 0; M < DL; ++M)
        seg[c.lbase + M * c.nbc + c.blk * 256 + t] = acc[M];
    }
    grp_combos<HALF, GRP, CI + 1>(cgp, x1r, x2r, seg, t);
  }
}

// ---- flush: 2 linear spans, 512 threads, f32x4 each.
template <int HALF>
__device__ __forceinline__ void flush_half(const float* __restrict__ seg,
                                           float* __restrict__ outrow,
                                           int tid) {
#pragma unroll
  for (int si = 0; si < 2; ++si) {
    const Span S = TAB.h[HALF].sp[si];
    const int NF4 = S.nf / 4;
    const f32x4* sb = reinterpret_cast<const f32x4*>(seg + S.lbase);
    f32x4* ob = reinterpret_cast<f32x4*>(outrow + S.gbase);
#pragma unroll
    for (int k = 0; k < (NF4 + 511) / 512; ++k) {
      const int idx = tid + 512 * k;
      if (idx < NF4) ob[idx] = sb[idx];
    }
  }
}

// ---- main: block = (sample, half). 512 threads = 2 combo-groups.
__global__ __launch_bounds__(512) void cg_main(
    const float* __restrict__ x1_0, const float* __restrict__ x2_0,
    const float* __restrict__ x1_1, const float* __restrict__ x2_1,
    const float* __restrict__ x1_2, const float* __restrict__ x2_2,
    const float* __restrict__ x1_3, const float* __restrict__ x2_3,
    const float* __restrict__ cgp_, float* __restrict__ out) {
  const float* cgp = (const float*)__builtin_assume_aligned(cgp_, 256);
  __shared__ __align__(16) float seg[20224];  // 79KB: half-row staging
  const int tid = (int)threadIdx.x;
  const int id = (int)blockIdx.x;
  const int n = id >> 1, half = id & 1;
  const int t = tid & 255;
  const int r = t >> 4, col = t & 15;
  // stage this sample's 2*256 input floats into seg[0:512] (scratch):
  // tid<256 loads x1 element (r,col), tid>=256 loads x2 element.
  {
    const float* s1; const float* s2; int ri;
    if (r < 1)      { s1 = x1_0 + n * 16;  s2 = x2_0 + n * 16;  ri = r; }
    else if (r < 4) { s1 = x1_1 + n * 48;  s2 = x2_1 + n * 48;  ri = r - 1; }
    else if (r < 9) { s1 = x1_2 + n * 80;  s2 = x2_2 + n * 80;  ri = r - 4; }
    else            { s1 = x1_3 + n * 112; s2 = x2_3 + n * 112; ri = r - 9; }
    if (tid < 256) seg[t] = s1[ri * 16 + col];
    else           seg[256 + t] = s2[ri * 16 + col];
  }
  __syncthreads();
  // hoist this thread's columns into registers (compile-time indexed)
  float x1r[16], x2r[16];
#pragma unroll
  for (int k = 0; k < 16; ++k) {
    x1r[k] = seg[k * 16 + r];          // p = r
    x2r[k] = seg[256 + k * 16 + col];  // q = col
  }
  __syncthreads();  // seg[0:512] dead; compute may overwrite it
  const int grp = tid >> 8;
  if (half == 0) {
    if (grp == 0) grp_combos<0, 0, 0>(cgp, x1r, x2r, seg, t);
    else          grp_combos<0, 1, 0>(cgp, x1r, x2r, seg, t);
  } else {
    if (grp == 0) grp_combos<1, 0, 0>(cgp, x1r, x2r, seg, t);
    else          grp_combos<1, 1, 0>(cgp, x1r, x2r, seg, t);
  }
  __syncthreads();
  float* outrow = out + (size_t)n * (size_t)TAB.outsize;
  if (half == 0) flush_half<0>(seg, outrow, tid);
  else           flush_half<1>(seg, outrow, tid);
}

}  // namespace

extern "C" void kernel_launch(void* const* d_in, const int* in_sizes, int n_in,
                              void* d_out, int out_size, void* d_ws,
                              size_t ws_size, hipStream_t stream) {
  const float* x1[4];
  const float* x2[4];
  // setup_inputs() dict order is interleaved (x1_l0, x2_l0, x1_l1, ...);
  // detect vs grouped (x1_l0..x1_l3, x2_l0..) via sizes.
  if (in_sizes[1] == in_sizes[0]) {
    for (int l = 0; l < 4; ++l) {
      x1[l] = (const float*)d_in[2 * l];
      x2[l] = (const float*)d_in[2 * l + 1];
    }
  } else {
    for (int l = 0; l < 4; ++l) {
      x1[l] = (const float*)d_in[l];
      x2[l] = (const float*)d_in[4 + l];
    }
  }
  const float* cg = (const float*)d_in[8];
  float* out = (float*)d_out;
  float* cgp = (float*)d_ws;  // packed coefficients (~16 KB)

  const int n = in_sizes[0] / 16;  // x?_l0 is (n, 1, 16)

  pack_cg_kernel<<<1, 256, 0, stream>>>(cg, cgp);
  cg_main<<<2 * n, 512, 0, stream>>>(x1[0], x2[0], x1[1], x2[1], x1[2],
                                     x2[2], x1[3], x2[3], cgp, out);
}